// Round 1
// 371.419 us; speedup vs baseline: 1.0324x; 1.0324x over previous
//
#include <hip/hip_runtime.h>

// RSSM rollout: B=16384 independent rows, T=64 sequential steps.
// One wave (64-thread block) owns 16 rows for the whole T loop; matmuls via
// v_mfma_f32_16x16x32_bf16 with weights held in registers as B-frags.
//
// Round-4 change: this block has exactly ONE wave, and per-wave LDS ops are
// processed in order by the DS pipe -> no __syncthreads() needed anywhere.
// The old per-step __syncthreads compiled to s_waitcnt vmcnt(0) lgkmcnt(0) +
// s_barrier, draining the 16 in-flight HBM output stores (and the actions
// load) every step -- the dominant stall at 1 wave/SIMD occupancy.
// Replaced with zero-cost wave_barrier() scheduling fences, plus a one-step
// register prefetch of actions, and the s-feedback LDS write moved ahead of
// the output stores / softplus (off the critical path).

#define NBATCH 16384
#define NSTEP  64
#define U_STRIDE 104   // row: s[0,32) a[32,40) h[40,72) zeros[72,96) pad[96,104)
#define HID_STRIDE 40  // 32 + pad

typedef short bf16x8 __attribute__((ext_vector_type(8)));
typedef short bf16x4 __attribute__((ext_vector_type(4)));
typedef float f32x4  __attribute__((ext_vector_type(4)));

__device__ __forceinline__ short f2bf(float f) {  // RNE fp32 -> bf16
    union { float f; unsigned int u; } c; c.f = f;
    unsigned int r = c.u + 0x7fffu + ((c.u >> 16) & 1u);
    return (short)(r >> 16);
}

__global__ __launch_bounds__(64) void rssm_kernel(
    const float* __restrict__ s0, const float* __restrict__ h0,
    const float* __restrict__ actions,
    const float* __restrict__ W_ih, const float* __restrict__ W_hh,
    const float* __restrict__ b_ih, const float* __restrict__ b_hh,
    const float* __restrict__ fc1_w, const float* __restrict__ fc1_b,
    const float* __restrict__ mean_w, const float* __restrict__ mean_b,
    const float* __restrict__ std_w, const float* __restrict__ std_b,
    float* __restrict__ out)
{
    __shared__ alignas(16) short u_lds[16 * U_STRIDE];
    __shared__ alignas(16) short hid_lds[16 * HID_STRIDE];

    const int lane = threadIdx.x;      // 0..63 (one wave per block)
    const int n    = lane & 15;
    const int q    = lane >> 4;
    const int base = blockIdx.x * 16;  // 16 batch rows per wave

    // ---- weight B-fragments: B[k][col] = W[col][k], col = hf*16+n, k = c*32+q*8+j
    bf16x8 wb[2][3], fw[2], mw[2], sw[2];
    #pragma unroll
    for (int hf = 0; hf < 2; ++hf) {
        const int col = hf * 16 + n;
        #pragma unroll
        for (int c = 0; c < 3; ++c)
            #pragma unroll
            for (int j = 0; j < 8; ++j) {
                const int k = c * 32 + q * 8 + j;
                float w = 0.f;
                if (k < 40)      w = W_ih[col * 40 + k];        // [s,a] part
                else if (k < 72) w = W_hh[col * 32 + (k - 40)]; // h part
                wb[hf][c][j] = f2bf(w);                          // k>=72: zero
            }
        #pragma unroll
        for (int j = 0; j < 8; ++j) {
            const int k = q * 8 + j;
            fw[hf][j] = f2bf(fc1_w [col * 32 + k]);
            mw[hf][j] = f2bf(mean_w[col * 32 + k]);
            sw[hf][j] = f2bf(std_w [col * 32 + k]);
        }
    }
    float bc[2], fb[2], mb[2], sb[2];
    #pragma unroll
    for (int hf = 0; hf < 2; ++hf) {
        const int col = hf * 16 + n;
        bc[hf] = b_ih[col] + b_hh[col];
        fb[hf] = fc1_b[col];
        mb[hf] = mean_b[col];
        sb[hf] = std_b[col];
    }

    // ---- init u tile: zero (k in [72,104) must stay 0), then s0/h0 (fp32->bf16)
    for (int i = lane; i < 16 * U_STRIDE; i += 64) u_lds[i] = 0;
    __builtin_amdgcn_wave_barrier();
    {
        const int m = lane >> 2;
        const int k = (lane & 3) * 8;
        bf16x8 sv, hv;
        #pragma unroll
        for (int j = 0; j < 8; ++j) {
            sv[j] = f2bf(s0[(size_t)(base + m) * 32 + k + j]);
            hv[j] = f2bf(h0[(size_t)(base + m) * 32 + k + j]);
        }
        *(bf16x8*)(&u_lds[m * U_STRIDE + k]) = sv;
        *(bf16x8*)(&u_lds[m * U_STRIDE + 40 + k]) = hv;
    }
    __builtin_amdgcn_wave_barrier();

    // ---- actions prefetch: lane<32, lane = 2*m + half, f32x4 per lane per step
    const int am = lane >> 1;
    const int ah = lane & 1;
    const float* aptr = actions + (size_t)(base + am) * (NSTEP * 8) + ah * 4;
    f32x4 a_next = {0.f, 0.f, 0.f, 0.f};
    if (lane < 32) a_next = *(const f32x4*)aptr;   // a_0

    for (int t = 0; t < NSTEP; ++t) {
        // stage a_t (from prefetch regs) and issue load of a_{t+1}
        if (lane < 32) {
            bf16x4 av;
            #pragma unroll
            for (int j = 0; j < 4; ++j) av[j] = f2bf(a_next[j]);
            *(bf16x4*)(&u_lds[am * U_STRIDE + 32 + ah * 4]) = av;
            if (t + 1 < NSTEP)
                a_next = *(const f32x4*)(aptr + (size_t)(t + 1) * 8);
        }
        __builtin_amdgcn_wave_barrier();

        // u A-frags: row = lane&15, k = c*32 + q*8 + j  (16B-aligned reads)
        // Same-wave DS RAW is ordered by the in-order LDS pipe; no barrier.
        bf16x8 ua0 = *(const bf16x8*)(&u_lds[n * U_STRIDE +  0 + q * 8]);
        bf16x8 ua1 = *(const bf16x8*)(&u_lds[n * U_STRIDE + 32 + q * 8]);
        bf16x8 ua2 = *(const bf16x8*)(&u_lds[n * U_STRIDE + 64 + q * 8]);

        f32x4 acc0 = {bc[0], bc[0], bc[0], bc[0]};
        f32x4 acc1 = {bc[1], bc[1], bc[1], bc[1]};
        acc0 = __builtin_amdgcn_mfma_f32_16x16x32_bf16(ua0, wb[0][0], acc0, 0, 0, 0);
        acc0 = __builtin_amdgcn_mfma_f32_16x16x32_bf16(ua1, wb[0][1], acc0, 0, 0, 0);
        acc0 = __builtin_amdgcn_mfma_f32_16x16x32_bf16(ua2, wb[0][2], acc0, 0, 0, 0);
        acc1 = __builtin_amdgcn_mfma_f32_16x16x32_bf16(ua0, wb[1][0], acc1, 0, 0, 0);
        acc1 = __builtin_amdgcn_mfma_f32_16x16x32_bf16(ua1, wb[1][1], acc1, 0, 0, 0);
        acc1 = __builtin_amdgcn_mfma_f32_16x16x32_bf16(ua2, wb[1][2], acc1, 0, 0, 0);

        // tanh -> h (bf16) into u h-section. C layout: row m = q*4+r, col = hf*16+n
        #pragma unroll
        for (int r = 0; r < 4; ++r) {
            const int m = q * 4 + r;
            float h0v = 1.f - 2.f / (__expf(2.f * acc0[r]) + 1.f);
            float h1v = 1.f - 2.f / (__expf(2.f * acc1[r]) + 1.f);
            u_lds[m * U_STRIDE + 40 + n]      = f2bf(h0v);
            u_lds[m * U_STRIDE + 40 + 16 + n] = f2bf(h1v);
        }
        __builtin_amdgcn_wave_barrier();

        // h as A-frag for fc1
        bf16x8 ha = *(const bf16x8*)(&u_lds[n * U_STRIDE + 40 + q * 8]);
        f32x4 f0 = {fb[0], fb[0], fb[0], fb[0]};
        f32x4 f1 = {fb[1], fb[1], fb[1], fb[1]};
        f0 = __builtin_amdgcn_mfma_f32_16x16x32_bf16(ha, fw[0], f0, 0, 0, 0);
        f1 = __builtin_amdgcn_mfma_f32_16x16x32_bf16(ha, fw[1], f1, 0, 0, 0);

        // elu -> hid tile
        #pragma unroll
        for (int r = 0; r < 4; ++r) {
            const int m = q * 4 + r;
            float x0 = f0[r], x1 = f1[r];
            float e0 = x0 > 0.f ? x0 : (__expf(x0) - 1.f);
            float e1 = x1 > 0.f ? x1 : (__expf(x1) - 1.f);
            hid_lds[m * HID_STRIDE + n]      = f2bf(e0);
            hid_lds[m * HID_STRIDE + 16 + n] = f2bf(e1);
        }
        __builtin_amdgcn_wave_barrier();

        bf16x8 da = *(const bf16x8*)(&hid_lds[n * HID_STRIDE + q * 8]);
        f32x4 m0 = {mb[0], mb[0], mb[0], mb[0]};
        f32x4 m1 = {mb[1], mb[1], mb[1], mb[1]};
        f32x4 v0 = {sb[0], sb[0], sb[0], sb[0]};
        f32x4 v1 = {sb[1], sb[1], sb[1], sb[1]};
        m0 = __builtin_amdgcn_mfma_f32_16x16x32_bf16(da, mw[0], m0, 0, 0, 0);
        m1 = __builtin_amdgcn_mfma_f32_16x16x32_bf16(da, mw[1], m1, 0, 0, 0);
        v0 = __builtin_amdgcn_mfma_f32_16x16x32_bf16(da, sw[0], v0, 0, 0, 0);
        v1 = __builtin_amdgcn_mfma_f32_16x16x32_bf16(da, sw[1], v1, 0, 0, 0);

        // critical path first: s_{t+1} = mean feedback into u s-section
        #pragma unroll
        for (int r = 0; r < 4; ++r) {
            const int m = q * 4 + r;
            u_lds[m * U_STRIDE + n]      = f2bf(m0[r]);
            u_lds[m * U_STRIDE + 16 + n] = f2bf(m1[r]);
        }
        __builtin_amdgcn_wave_barrier();

        // outputs (FP32), off the critical path. out[t][b][0:32]=mean,
        // [32:64]=softplus(std)+1e-5. Stores are fire-and-forget: with no
        // s_barrier in the loop, nothing ever drains vmcnt(0) on them.
        const size_t ob = (size_t)t * NBATCH * 64;
        #pragma unroll
        for (int r = 0; r < 4; ++r) {
            const int m = q * 4 + r;
            const size_t row = ob + (size_t)(base + m) * 64;
            out[row + n]      = m0[r];
            out[row + 16 + n] = m1[r];
            float x0 = v0[r], x1 = v1[r];
            float sp0 = fmaxf(x0, 0.f) + __logf(1.f + __expf(-fabsf(x0)));
            float sp1 = fmaxf(x1, 0.f) + __logf(1.f + __expf(-fabsf(x1)));
            out[row + 32 + n] = sp0 + 1e-5f;
            out[row + 48 + n] = sp1 + 1e-5f;
        }
    }
}

extern "C" void kernel_launch(void* const* d_in, const int* in_sizes, int n_in,
                              void* d_out, int out_size, void* d_ws, size_t ws_size,
                              hipStream_t stream) {
    (void)in_sizes; (void)n_in; (void)out_size; (void)d_ws; (void)ws_size;
    rssm_kernel<<<dim3(NBATCH / 16), dim3(64), 0, stream>>>(
        (const float*)d_in[0],  (const float*)d_in[1],  (const float*)d_in[2],
        (const float*)d_in[3],  (const float*)d_in[4],  (const float*)d_in[5],
        (const float*)d_in[6],  (const float*)d_in[7],  (const float*)d_in[8],
        (const float*)d_in[9],  (const float*)d_in[10], (const float*)d_in[11],
        (const float*)d_in[12], (float*)d_out);
}

// Round 3
// 353.929 us; speedup vs baseline: 1.0834x; 1.0494x over previous
//
#include <hip/hip_runtime.h>

// RSSM rollout: B=16384 independent rows, T=64 sequential steps.
// One wave (64-thread block) owns 16 rows for the whole T loop; matmuls via
// v_mfma_f32_16x16x32_bf16 with weights held in registers as B-frags.
//
// Round-5/6: the T-loop is GLOBALLY LOAD-FREE. vmcnt is a single in-order
// counter shared by loads and stores, so any per-step load could only be
// consumed after ALL previously-issued output stores retired -- a hidden
// full store-drain every step (why removing s_barrier in round-4 changed
// little). All actions are converted to bf16 and staged into LDS at init.
// The RNN input is laid out as k = [s(32) | h(32) | a(8)+zeros(24)] so the
// action slice is its own MFMA A-fragment read directly from action-LDS
// (q==0 lanes carry data, q>=1 feed a zero frag): no per-step action
// staging. 3 wave_barrier fences per step; the epilogue (softplus + stores)
// is un-fenced against the next iteration so it interleaves with the next
// step's LDS reads. Stores in the loop are never waited on.

#define NBATCH 16384
#define NSTEP  64
#define U_STRIDE 72    // row: s[0,32) h[32,64) pad[64,72)  (144B, 16B-aligned)
#define HID_STRIDE 40  // 32 + pad

typedef short bf16x8 __attribute__((ext_vector_type(8)));
typedef float f32x4  __attribute__((ext_vector_type(4)));

__device__ __forceinline__ short f2bf(float f) {  // RNE fp32 -> bf16
    union { float f; unsigned int u; } c; c.f = f;
    unsigned int r = c.u + 0x7fffu + ((c.u >> 16) & 1u);
    return (short)(r >> 16);
}

__global__ __launch_bounds__(64) void rssm_kernel(
    const float* __restrict__ s0, const float* __restrict__ h0,
    const float* __restrict__ actions,
    const float* __restrict__ W_ih, const float* __restrict__ W_hh,
    const float* __restrict__ b_ih, const float* __restrict__ b_hh,
    const float* __restrict__ fc1_w, const float* __restrict__ fc1_b,
    const float* __restrict__ mean_w, const float* __restrict__ mean_b,
    const float* __restrict__ std_w, const float* __restrict__ std_b,
    float* __restrict__ out)
{
    __shared__ alignas(16) short u_lds[16 * U_STRIDE];
    __shared__ alignas(16) short act_lds[NSTEP * 16 * 8];   // [t][row][8] bf16
    __shared__ alignas(16) short hid_lds[16 * HID_STRIDE];

    const int lane = threadIdx.x;      // 0..63 (one wave per block)
    const int n    = lane & 15;
    const int q    = lane >> 4;
    const int base = blockIdx.x * 16;  // 16 batch rows per wave

    // ---- weight B-fragments. k-layout: [s(0..31) | h(32..63) | a(64..71) | 0]
    // B[k][col] = W[col][k], col = hf*16+n, k = c*32 + q*8 + j
    bf16x8 wb[2][3], fw[2], mw[2], sw[2];
    #pragma unroll
    for (int hf = 0; hf < 2; ++hf) {
        const int col = hf * 16 + n;
        #pragma unroll
        for (int c = 0; c < 3; ++c)
            #pragma unroll
            for (int j = 0; j < 8; ++j) {
                const int kk = q * 8 + j;                       // 0..31 within slice
                float w = 0.f;
                if (c == 0)              w = W_ih[col * 40 + kk];        // s part
                else if (c == 1)         w = W_hh[col * 32 + kk];        // h part
                else if (kk < 8)         w = W_ih[col * 40 + 32 + kk];   // a part
                wb[hf][c][j] = f2bf(w);
            }
        #pragma unroll
        for (int j = 0; j < 8; ++j) {
            const int k = q * 8 + j;
            fw[hf][j] = f2bf(fc1_w [col * 32 + k]);
            mw[hf][j] = f2bf(mean_w[col * 32 + k]);
            sw[hf][j] = f2bf(std_w [col * 32 + k]);
        }
    }
    float bc[2], fb[2], mb[2], sb[2];
    #pragma unroll
    for (int hf = 0; hf < 2; ++hf) {
        const int col = hf * 16 + n;
        bc[hf] = b_ih[col] + b_hh[col];
        fb[hf] = fc1_b[col];
        mb[hf] = mean_b[col];
        sb[hf] = std_b[col];
    }

    // ---- init u tile: s0 / h0 (fp32 -> bf16)
    {
        const int m = lane >> 2;
        const int k = (lane & 3) * 8;
        bf16x8 sv, hv;
        #pragma unroll
        for (int j = 0; j < 8; ++j) {
            sv[j] = f2bf(s0[(size_t)(base + m) * 32 + k + j]);
            hv[j] = f2bf(h0[(size_t)(base + m) * 32 + k + j]);
        }
        *(bf16x8*)(&u_lds[m * U_STRIDE + k]) = sv;
        *(bf16x8*)(&u_lds[m * U_STRIDE + 32 + k]) = hv;
    }

    // ---- stage ALL actions to LDS as bf16: act_lds[t][row][8]
    {
        const int arow = lane & 15;
        const int aq   = lane >> 4;
        const float* ap = actions + (size_t)(base + arow) * (NSTEP * 8);
        #pragma unroll
        for (int tt = 0; tt < 16; ++tt) {
            const int t = tt * 4 + aq;
            const f32x4 lo = *(const f32x4*)(ap + t * 8);
            const f32x4 hi = *(const f32x4*)(ap + t * 8 + 4);
            bf16x8 av;
            #pragma unroll
            for (int j = 0; j < 4; ++j) { av[j] = f2bf(lo[j]); av[4 + j] = f2bf(hi[j]); }
            *(bf16x8*)(&act_lds[(t * 16 + arow) * 8]) = av;
        }
    }
    __builtin_amdgcn_wave_barrier();

    // ---- per-row output pointers (strength-reduced; step stride = 4 MB)
    float* outp[4];
    #pragma unroll
    for (int r = 0; r < 4; ++r)
        outp[r] = out + (size_t)(base + q * 4 + r) * 64 + n;

    const bf16x8 zfrag = {0, 0, 0, 0, 0, 0, 0, 0};

    for (int t = 0; t < NSTEP; ++t) {
        // u A-frags: row = n, k = c*32 + q*8 + j. Action slice straight from
        // act_lds (only q==0 holds k=64..71; q>=1 lanes are the zero region).
        bf16x8 ua0 = *(const bf16x8*)(&u_lds[n * U_STRIDE + q * 8]);
        bf16x8 ua1 = *(const bf16x8*)(&u_lds[n * U_STRIDE + 32 + q * 8]);
        bf16x8 af  = zfrag;
        if (q == 0) af = *(const bf16x8*)(&act_lds[(t * 16 + n) * 8]);

        f32x4 acc0 = {bc[0], bc[0], bc[0], bc[0]};
        f32x4 acc1 = {bc[1], bc[1], bc[1], bc[1]};
        acc0 = __builtin_amdgcn_mfma_f32_16x16x32_bf16(ua0, wb[0][0], acc0, 0, 0, 0);
        acc0 = __builtin_amdgcn_mfma_f32_16x16x32_bf16(ua1, wb[0][1], acc0, 0, 0, 0);
        acc0 = __builtin_amdgcn_mfma_f32_16x16x32_bf16(af,  wb[0][2], acc0, 0, 0, 0);
        acc1 = __builtin_amdgcn_mfma_f32_16x16x32_bf16(ua0, wb[1][0], acc1, 0, 0, 0);
        acc1 = __builtin_amdgcn_mfma_f32_16x16x32_bf16(ua1, wb[1][1], acc1, 0, 0, 0);
        acc1 = __builtin_amdgcn_mfma_f32_16x16x32_bf16(af,  wb[1][2], acc1, 0, 0, 0);

        // tanh -> h (bf16) into u h-section. C layout: row m = q*4+r, col = hf*16+n
        #pragma unroll
        for (int r = 0; r < 4; ++r) {
            const int m = q * 4 + r;
            float h0v = 1.f - 2.f / (__expf(2.f * acc0[r]) + 1.f);
            float h1v = 1.f - 2.f / (__expf(2.f * acc1[r]) + 1.f);
            u_lds[m * U_STRIDE + 32 + n]      = f2bf(h0v);
            u_lds[m * U_STRIDE + 32 + 16 + n] = f2bf(h1v);
        }
        __builtin_amdgcn_wave_barrier();

        // h as A-frag for fc1
        bf16x8 ha = *(const bf16x8*)(&u_lds[n * U_STRIDE + 32 + q * 8]);
        f32x4 f0 = {fb[0], fb[0], fb[0], fb[0]};
        f32x4 f1 = {fb[1], fb[1], fb[1], fb[1]};
        f0 = __builtin_amdgcn_mfma_f32_16x16x32_bf16(ha, fw[0], f0, 0, 0, 0);
        f1 = __builtin_amdgcn_mfma_f32_16x16x32_bf16(ha, fw[1], f1, 0, 0, 0);

        // elu -> hid tile
        #pragma unroll
        for (int r = 0; r < 4; ++r) {
            const int m = q * 4 + r;
            float x0 = f0[r], x1 = f1[r];
            float e0 = x0 > 0.f ? x0 : (__expf(x0) - 1.f);
            float e1 = x1 > 0.f ? x1 : (__expf(x1) - 1.f);
            hid_lds[m * HID_STRIDE + n]      = f2bf(e0);
            hid_lds[m * HID_STRIDE + 16 + n] = f2bf(e1);
        }
        __builtin_amdgcn_wave_barrier();

        bf16x8 da = *(const bf16x8*)(&hid_lds[n * HID_STRIDE + q * 8]);
        f32x4 m0 = {mb[0], mb[0], mb[0], mb[0]};
        f32x4 m1 = {mb[1], mb[1], mb[1], mb[1]};
        f32x4 v0 = {sb[0], sb[0], sb[0], sb[0]};
        f32x4 v1 = {sb[1], sb[1], sb[1], sb[1]};
        m0 = __builtin_amdgcn_mfma_f32_16x16x32_bf16(da, mw[0], m0, 0, 0, 0);
        m1 = __builtin_amdgcn_mfma_f32_16x16x32_bf16(da, mw[1], m1, 0, 0, 0);
        v0 = __builtin_amdgcn_mfma_f32_16x16x32_bf16(da, sw[0], v0, 0, 0, 0);
        v1 = __builtin_amdgcn_mfma_f32_16x16x32_bf16(da, sw[1], v1, 0, 0, 0);

        // critical path first: s_{t+1} = mean feedback into u s-section
        #pragma unroll
        for (int r = 0; r < 4; ++r) {
            const int m = q * 4 + r;
            u_lds[m * U_STRIDE + n]      = f2bf(m0[r]);
            u_lds[m * U_STRIDE + 16 + n] = f2bf(m1[r]);
        }
        __builtin_amdgcn_wave_barrier();

        // epilogue (FP32 out), off the critical path and un-fenced against the
        // next iteration: out[t][b][0:32]=mean, [32:64]=softplus(std)+1e-5.
        // No vmem load exists in the loop, so these stores are never waited on.
        #pragma unroll
        for (int r = 0; r < 4; ++r) {
            float x0 = v0[r], x1 = v1[r];
            float sp0 = fmaxf(x0, 0.f) + __logf(1.f + __expf(-fabsf(x0)));
            float sp1 = fmaxf(x1, 0.f) + __logf(1.f + __expf(-fabsf(x1)));
            float* p = outp[r];
            p[0]  = m0[r];
            p[16] = m1[r];
            p[32] = sp0 + 1e-5f;
            p[48] = sp1 + 1e-5f;
            outp[r] += (size_t)NBATCH * 64;
        }
    }
}

extern "C" void kernel_launch(void* const* d_in, const int* in_sizes, int n_in,
                              void* d_out, int out_size, void* d_ws, size_t ws_size,
                              hipStream_t stream) {
    (void)in_sizes; (void)n_in; (void)out_size; (void)d_ws; (void)ws_size;
    rssm_kernel<<<dim3(NBATCH / 16), dim3(64), 0, stream>>>(
        (const float*)d_in[0],  (const float*)d_in[1],  (const float*)d_in[2],
        (const float*)d_in[3],  (const float*)d_in[4],  (const float*)d_in[5],
        (const float*)d_in[6],  (const float*)d_in[7],  (const float*)d_in[8],
        (const float*)d_in[9],  (const float*)d_in[10], (const float*)d_in[11],
        (const float*)d_in[12], (float*)d_out);
}